// Round 1
// baseline (1319.216 us; speedup 1.0000x reference)
//
#include <hip/hip_runtime.h>
#include <hip/hip_bf16.h>
#include <stdint.h>

// B=8, N=E=2048.
// Pipeline:
//  1) split X, W into bf16 (hi, lo) pairs         [precision: 16-bit mantissa]
//  2) Q = X W^T + b   (split-3 MFMA, epilogue re-splits Q into hi/lo bf16)
//  3) S[b,n,m] = Q[n,:].X[m,:] + gamma  (split-3 MFMA, fp32 out)
//  4) column softmax over n: M[b,m]=max_n S, R[b,m]=1/sum_n exp(S-M)
//     (split-8 partial reduction over n + combine)
//  5) attn[b,m,e] = exp(S[b,m,e]-M[b,e])*R[b,e] -> bf16, row-major [m,e]
//  6) out[b,n,m] = X[n,:].attn[m,:]  (single-pass bf16 MFMA, fp32 out)

typedef unsigned short u16;
typedef __bf16 bf16x8 __attribute__((ext_vector_type(8)));
typedef float f32x4 __attribute__((ext_vector_type(4)));

#define ND 2048
#define NBATCH 8
#define NNL 4194304L  // ND*ND

static __device__ __forceinline__ u16 f2bf(float f) {
  uint32_t x = __float_as_uint(f);
  x += 0x7fffu + ((x >> 16) & 1u);  // round to nearest even
  return (u16)(x >> 16);
}
static __device__ __forceinline__ float bf2f(u16 u) {
  return __uint_as_float(((uint32_t)u) << 16);
}

static __device__ __forceinline__ void stage16(const void* g, void* l) {
  __builtin_amdgcn_global_load_lds(
      (const __attribute__((address_space(1))) uint32_t*)g,
      (__attribute__((address_space(3))) uint32_t*)l, 16, 0, 0);
}

// ---------------- fp32 -> bf16 hi/lo split ----------------
__global__ void split_fp32_bf16(const float* __restrict__ x, u16* __restrict__ hi,
                                u16* __restrict__ lo, int n4) {
  int i = blockIdx.x * 256 + threadIdx.x;
  if (i >= n4) return;
  float4 v = reinterpret_cast<const float4*>(x)[i];
  ushort4 h, l;
  h.x = f2bf(v.x); l.x = f2bf(v.x - bf2f(h.x));
  h.y = f2bf(v.y); l.y = f2bf(v.y - bf2f(h.y));
  h.z = f2bf(v.z); l.z = f2bf(v.z - bf2f(h.z));
  h.w = f2bf(v.w); l.w = f2bf(v.w - bf2f(h.w));
  reinterpret_cast<ushort4*>(hi)[i] = h;
  reinterpret_cast<ushort4*>(lo)[i] = l;
}

// ---------------- GEMM: C[i,j] = dot(A[i,:], B[j,:])  (both row-major, K=2048)
// MODE 0: split-3 inputs, fp32 out + gamma scalar
// MODE 1: split-3 inputs, out re-split to bf16 hi/lo + bias[j]
// MODE 2: single-pass bf16 inputs (hi only), fp32 out
template <int MODE>
__launch_bounds__(256) __global__
void gemm_bt(const u16* __restrict__ Ahi, const u16* __restrict__ Alo, long sA,
             const u16* __restrict__ Bhi, const u16* __restrict__ Blo, long sB,
             const float* __restrict__ bias, const float* __restrict__ gamma,
             float* __restrict__ Cf, u16* __restrict__ Chi, u16* __restrict__ Clo) {
  constexpr bool SPLIT = (MODE != 2);
  constexpr int BM = 128, BK = 32;
  __shared__ u16 smem[(SPLIT ? 4 : 2) * BM * BK];
  u16* sAh = smem;
  u16* sBh = smem + BM * BK;
  u16* sAl = SPLIT ? smem + 2 * BM * BK : smem;
  u16* sBl = SPLIT ? smem + 3 * BM * BK : smem;

  const int b = blockIdx.z;
  const long tm = (long)blockIdx.y * BM;
  const long tn = (long)blockIdx.x * BM;
  const int tid = threadIdx.x;
  const int wave = tid >> 6;
  const int lane = tid & 63;
  const int wm = (wave >> 1) << 6;  // wave 2x2 grid, 64x64 each
  const int wn = (wave & 1) << 6;

  const u16* pAhi = Ahi + b * sA + tm * ND;
  const u16* pBhi = Bhi + b * sB + tn * ND;

  // staging assignment: each wave owns chunks of one (or half a) tile.
  const u16* gsrc;
  u16* ldst;
  int cbase, nch;
  if constexpr (SPLIT) {
    const u16* pAlo = Alo + b * sA + tm * ND;
    const u16* pBlo = Blo + b * sB + tn * ND;
    gsrc = (wave == 0) ? pAhi : (wave == 1) ? pBhi : (wave == 2) ? pAlo : pBlo;
    ldst = (wave == 0) ? sAh : (wave == 1) ? sBh : (wave == 2) ? sAl : sBl;
    cbase = 0; nch = 8;
  } else {
    gsrc = (wave < 2) ? pAhi : pBhi;
    ldst = (wave < 2) ? sAh : sBh;
    cbase = (wave & 1) * 4; nch = 4;
  }
  // lane -> (row = lane>>2 within 16-row chunk, 16B segment = lane&3); matches
  // LDS dest = chunk_base + lane*16 for row-major [128][32] bf16 tiles.
  const char* gb = (const char*)gsrc + (long)(lane >> 2) * (ND * 2) + (lane & 3) * 16;
  char* lb = (char*)ldst;

  f32x4 acc[4][4] = {};

  const int arow = (wm + (lane & 15)) * BK + ((lane >> 4) << 3);
  const int brow = (wn + (lane & 15)) * BK + ((lane >> 4) << 3);

  for (int k0 = 0; k0 < ND; k0 += BK) {
#pragma unroll
    for (int i = 0; i < nch; ++i) {
      int c = cbase + i;
      stage16(gb + (long)c * 16 * (ND * 2) + k0 * 2, lb + c * 1024);
    }
    asm volatile("s_waitcnt vmcnt(0)" ::: "memory");
    __syncthreads();

    bf16x8 ah[4], bh[4], al[4], bl[4];
#pragma unroll
    for (int t = 0; t < 4; ++t) {
      ah[t] = *(const bf16x8*)&sAh[arow + t * 16 * BK];
      bh[t] = *(const bf16x8*)&sBh[brow + t * 16 * BK];
      if constexpr (SPLIT) {
        al[t] = *(const bf16x8*)&sAl[arow + t * 16 * BK];
        bl[t] = *(const bf16x8*)&sBl[brow + t * 16 * BK];
      }
    }
#pragma unroll
    for (int mt = 0; mt < 4; ++mt) {
#pragma unroll
      for (int nt = 0; nt < 4; ++nt) {
        acc[mt][nt] = __builtin_amdgcn_mfma_f32_16x16x32_bf16(ah[mt], bh[nt], acc[mt][nt], 0, 0, 0);
        if constexpr (SPLIT) {
          acc[mt][nt] = __builtin_amdgcn_mfma_f32_16x16x32_bf16(ah[mt], bl[nt], acc[mt][nt], 0, 0, 0);
          acc[mt][nt] = __builtin_amdgcn_mfma_f32_16x16x32_bf16(al[mt], bh[nt], acc[mt][nt], 0, 0, 0);
        }
      }
    }
    __syncthreads();
  }

  // epilogue: C/D layout col=lane&15, row=(lane>>4)*4+reg  [verified m89/m91]
  const int rr = (lane >> 4) << 2;
  const int cc = lane & 15;
  if constexpr (MODE == 1) {
#pragma unroll
    for (int nt = 0; nt < 4; ++nt) {
      const long col = tn + wn + nt * 16 + cc;
      const float bj = bias[col];
#pragma unroll
      for (int mt = 0; mt < 4; ++mt) {
#pragma unroll
        for (int r = 0; r < 4; ++r) {
          const long row = tm + wm + mt * 16 + rr + r;
          const float q = acc[mt][nt][r] + bj;
          const u16 h = f2bf(q);
          const u16 l = f2bf(q - bf2f(h));
          const long idx = (long)b * NNL + row * ND + col;
          Chi[idx] = h;
          Clo[idx] = l;
        }
      }
    }
  } else {
    const float g = (MODE == 0) ? gamma[0] : 0.0f;
#pragma unroll
    for (int mt = 0; mt < 4; ++mt) {
#pragma unroll
      for (int nt = 0; nt < 4; ++nt) {
#pragma unroll
        for (int r = 0; r < 4; ++r) {
          const long row = tm + wm + mt * 16 + rr + r;
          const long col = tn + wn + nt * 16 + cc;
          Cf[(long)b * NNL + row * ND + col] = acc[mt][nt][r] + g;
        }
      }
    }
  }
}

// ---------------- column-softmax stats (reduce over n, per column m) ----------
__global__ void stats_partial(const float* __restrict__ S, float* __restrict__ Mp,
                              float* __restrict__ Sp) {
  const int col = blockIdx.x * 256 + threadIdx.x;  // 0..2047
  const int seg = blockIdx.y;                      // 0..7 (n-split)
  const int b = blockIdx.z;
  const float* p = S + (long)b * NNL + (long)seg * 256 * ND + col;
  float m = -3.4e38f, s = 0.f;
  for (int n = 0; n < 256; ++n) {
    float x = p[(long)n * ND];
    float nm = fmaxf(m, x);
    s = s * __expf(m - nm) + __expf(x - nm);
    m = nm;
  }
  const long o = ((long)b * 8 + seg) * ND + col;
  Mp[o] = m;
  Sp[o] = s;
}

__global__ void stats_combine(const float* __restrict__ Mp, const float* __restrict__ Sp,
                              float* __restrict__ Mx, float* __restrict__ Rs) {
  const int col = blockIdx.x * 256 + threadIdx.x;
  const int b = blockIdx.y;
  float m = -3.4e38f, s = 0.f;
  for (int k = 0; k < 8; ++k) {
    const long o = ((long)b * 8 + k) * ND + col;
    float mk = Mp[o], sk = Sp[o];
    float nm = fmaxf(m, mk);
    s = s * __expf(m - nm) + sk * __expf(mk - nm);
    m = nm;
  }
  Mx[(long)b * ND + col] = m;
  Rs[(long)b * ND + col] = 1.0f / s;
}

// attn[b,m,e] = exp(S[b,m,e] - Mx[b,e]) * Rs[b,e]  -> bf16, same layout as S
__global__ void scale_exp_kernel(const float* __restrict__ S, const float* __restrict__ Mx,
                                 const float* __restrict__ Rs, u16* __restrict__ A) {
  const long i4 = (long)blockIdx.x * 256 + threadIdx.x;  // total/4
  const long i = i4 * 4;
  const int b = (int)(i >> 22);       // N*N = 2^22
  const int col = (int)(i & 2047);    // e index (multiple of 4)
  float4 s = reinterpret_cast<const float4*>(S)[i4];
  float4 m4 = *reinterpret_cast<const float4*>(&Mx[(long)b * ND + col]);
  float4 r4 = *reinterpret_cast<const float4*>(&Rs[(long)b * ND + col]);
  ushort4 o;
  o.x = f2bf(__expf(s.x - m4.x) * r4.x);
  o.y = f2bf(__expf(s.y - m4.y) * r4.y);
  o.z = f2bf(__expf(s.z - m4.z) * r4.z);
  o.w = f2bf(__expf(s.w - m4.w) * r4.w);
  reinterpret_cast<ushort4*>(A)[i4] = o;
}

// ---------------- launch ----------------
extern "C" void kernel_launch(void* const* d_in, const int* in_sizes, int n_in,
                              void* d_out, int out_size, void* d_ws, size_t ws_size,
                              hipStream_t stream) {
  (void)in_sizes; (void)n_in; (void)out_size;
  const float* X = (const float*)d_in[0];     // [8,2048,2048]
  const float* W = (const float*)d_in[1];     // [2048,2048]
  const float* bias = (const float*)d_in[2];  // [2048]
  const float* gamma = (const float*)d_in[3]; // scalar

  char* ws = (char*)d_ws;
  // layout (bytes): needs 420,610,048 total
  u16* Xhi = (u16*)(ws);
  u16* Xlo = (u16*)(ws + 67108864L);
  u16* Whi = (u16*)(ws + 134217728L);
  u16* Wlo = (u16*)(ws + 142606336L);
  u16* Qhi = (u16*)(ws + 150994944L);
  u16* Qlo = (u16*)(ws + 218103808L);
  float* S = (float*)(ws + 285212672L);
  float* Mp = (float*)(ws + 419430400L);
  float* Sp = (float*)(ws + 419954688L);
  float* Mx = (float*)(ws + 420478976L);
  float* Rs = (float*)(ws + 420544512L);
  u16* Amat = Qhi;  // overlay: Q is dead after GEMM2 (stream-ordered)
  if (ws_size < 420610048UL) return;  // fail loudly via absmax rather than corrupt

  split_fp32_bf16<<<32768, 256, 0, stream>>>(X, Xhi, Xlo, 8388608);
  split_fp32_bf16<<<4096, 256, 0, stream>>>(W, Whi, Wlo, 1048576);

  dim3 gg(16, 16, 8), bb(256);
  // Q[b,n,f] = sum_e X[b,n,e] W[f,e] + bias[f]  -> split bf16
  gemm_bt<1><<<gg, bb, 0, stream>>>(Xhi, Xlo, NNL, Whi, Wlo, 0L, bias, nullptr,
                                    nullptr, Qhi, Qlo);
  // S[b,n,m] = sum_e Q[b,n,e] X[b,m,e] + gamma  -> fp32
  gemm_bt<0><<<gg, bb, 0, stream>>>(Qhi, Qlo, NNL, Xhi, Xlo, NNL, nullptr, gamma,
                                    S, nullptr, nullptr);
  // softmax over axis n (per column m)
  stats_partial<<<dim3(8, 8, 8), 256, 0, stream>>>(S, Mp, Sp);
  stats_combine<<<dim3(8, 8), 256, 0, stream>>>(Mp, Sp, Mx, Rs);
  scale_exp_kernel<<<32768, 256, 0, stream>>>(S, Mx, Rs, Amat);
  // out[b,n,m] = sum_e X[b,n,e] attn[b,m,e]  -> fp32 d_out
  gemm_bt<2><<<gg, bb, 0, stream>>>(Xhi, nullptr, NNL, Amat, nullptr, NNL, nullptr,
                                    nullptr, (float*)d_out, nullptr, nullptr);
}

// Round 2
// 1151.950 us; speedup vs baseline: 1.1452x; 1.1452x over previous
//
#include <hip/hip_runtime.h>
#include <hip/hip_bf16.h>
#include <stdint.h>

// B=8, N=E=2048.  All-fp16 pipeline with split-2 (A-side-corrected) GEMMs:
//  1) X -> (Xhi, Xlo) fp16 pair; W -> Whi fp16
//  2) Q = (Xhi+Xlo)·Whi^T + b   (2 MFMA products; epilogue re-splits Q to fp16 hi/lo)
//  3) S = (Qhi+Qlo)·Xhi^T + gamma  (2 products, fp32 out)
//  4) column softmax stats over n (split-8 + combine)
//  5) attn[b,m,e] = exp(S-M)*R -> fp16 row-major [m,e]
//  6) out = Xhi·attn^T  (1 product, fp32 out)
// Error budget: score noise sigma ~0.018 (GEMM1 W-rounding 0.013 + GEMM2
// X-rounding 0.013); near-tie softmax columns give Δout ~0.13 worst-case;
// GEMM3 fp16 noise ~0.01.  Threshold 0.205.

typedef _Float16 f16;
typedef f16 f16x8 __attribute__((ext_vector_type(8)));
typedef f16 f16x4 __attribute__((ext_vector_type(4)));
typedef float f32x4 __attribute__((ext_vector_type(4)));

#define ND 2048
#define NNL 4194304L  // ND*ND

static __device__ __forceinline__ void stage16(const void* g, void* l) {
  __builtin_amdgcn_global_load_lds(
      (const __attribute__((address_space(1))) uint32_t*)g,
      (__attribute__((address_space(3))) uint32_t*)l, 16, 0, 0);
}

// ---------------- fp32 -> fp16 hi/lo split ----------------
__global__ void split_x_f16(const float* __restrict__ x, f16* __restrict__ hi,
                            f16* __restrict__ lo, int n4) {
  int i = blockIdx.x * 256 + threadIdx.x;
  if (i >= n4) return;
  float4 v = reinterpret_cast<const float4*>(x)[i];
  f16x4 h, l;
  h.x = (f16)v.x; l.x = (f16)(v.x - (float)h.x);
  h.y = (f16)v.y; l.y = (f16)(v.y - (float)h.y);
  h.z = (f16)v.z; l.z = (f16)(v.z - (float)h.z);
  h.w = (f16)v.w; l.w = (f16)(v.w - (float)h.w);
  reinterpret_cast<f16x4*>(hi)[i] = h;
  reinterpret_cast<f16x4*>(lo)[i] = l;
}

__global__ void split_w_f16(const float* __restrict__ x, f16* __restrict__ hi, int n4) {
  int i = blockIdx.x * 256 + threadIdx.x;
  if (i >= n4) return;
  float4 v = reinterpret_cast<const float4*>(x)[i];
  f16x4 h;
  h.x = (f16)v.x; h.y = (f16)v.y; h.z = (f16)v.z; h.w = (f16)v.w;
  reinterpret_cast<f16x4*>(hi)[i] = h;
}

// ---------------- GEMM: C[i,j] = dot(A[i,:], B[j,:])  (row-major, K=2048)
// MODE 1: A split-2 (hi+lo), epilogue bias + fp16 hi/lo split store (GEMM1)
// MODE 0: A split-2 (hi+lo), epilogue gamma + fp32 store            (GEMM2)
// MODE 2: single product, fp32 store                                 (GEMM3)
template <int MODE>
__launch_bounds__(256) __global__
void gemm_bt(const f16* __restrict__ Ahi, const f16* __restrict__ Alo, long sA,
             const f16* __restrict__ Bhi, long sB,
             const float* __restrict__ bias, const float* __restrict__ gamma,
             float* __restrict__ Cf, f16* __restrict__ Chi, f16* __restrict__ Clo) {
  constexpr bool SPLIT = (MODE != 2);
  constexpr int NT = SPLIT ? 3 : 2;   // staged tiles: {Ahi, Alo, Bhi} or {Ahi, Bhi}
  __shared__ f16 smem[NT * 4096];     // 128x32 fp16 per tile (8 KB)
  f16* sAh = smem;
  f16* sAl = smem + 4096;                      // SPLIT only
  f16* sBh = smem + (SPLIT ? 8192 : 4096);

  const int b = blockIdx.z;
  const long tm = (long)blockIdx.y * 128;
  const long tn = (long)blockIdx.x * 128;
  const int tid = threadIdx.x;
  const int wave = tid >> 6;
  const int lane = tid & 63;
  const int wm = (wave >> 1) << 6;  // wave 2x2 grid, 64x64 each
  const int wn = (wave & 1) << 6;

  const f16* tp[NT];
  tp[0] = Ahi + b * sA + tm * ND;
  if constexpr (SPLIT) {
    tp[1] = Alo + b * sA + tm * ND;
    tp[2] = Bhi + b * sB + tn * ND;
  } else {
    tp[1] = Bhi + b * sB + tn * ND;
  }

  // staging: NT*8 chunks of 16 rows; each wave owns 2*NT consecutive chunks.
  // lane -> (row = lane>>2 within chunk, 16B segment = lane&3); LDS dest is
  // chunk_base + lane*16 (wave-uniform base + lane*size, required by
  // global_load_lds).
  constexpr int NCH = 2 * NT;
  const char* gb[NCH];
  uint32_t loff[NCH];
#pragma unroll
  for (int i = 0; i < NCH; ++i) {
    const int c = wave * NCH + i;
    const int t = c >> 3;
    const int r = c & 7;
    gb[i] = (const char*)tp[t] + (long)(r * 16 + (lane >> 2)) * (ND * 2) + (lane & 3) * 16;
    loff[i] = t * 8192 + r * 1024 + lane * 16;
  }

  f32x4 acc[4][4] = {};
  const int arow = (wm + (lane & 15)) * 32 + ((lane >> 4) << 3);
  const int brow = (wn + (lane & 15)) * 32 + ((lane >> 4) << 3);

  for (int k0 = 0; k0 < ND; k0 += 32) {
#pragma unroll
    for (int i = 0; i < NCH; ++i)
      stage16(gb[i] + (long)k0 * 2, (char*)smem + loff[i]);
    asm volatile("s_waitcnt vmcnt(0)" ::: "memory");
    __syncthreads();

    f16x8 ah[4], al[4], bh[4];
#pragma unroll
    for (int t = 0; t < 4; ++t) {
      ah[t] = *(const f16x8*)&sAh[arow + t * 512];
      bh[t] = *(const f16x8*)&sBh[brow + t * 512];
      if constexpr (SPLIT) al[t] = *(const f16x8*)&sAl[arow + t * 512];
    }
#pragma unroll
    for (int mt = 0; mt < 4; ++mt) {
#pragma unroll
      for (int nt = 0; nt < 4; ++nt) {
        acc[mt][nt] = __builtin_amdgcn_mfma_f32_16x16x32_f16(ah[mt], bh[nt], acc[mt][nt], 0, 0, 0);
        if constexpr (SPLIT)
          acc[mt][nt] = __builtin_amdgcn_mfma_f32_16x16x32_f16(al[mt], bh[nt], acc[mt][nt], 0, 0, 0);
      }
    }
    __syncthreads();
  }

  // epilogue: C/D layout col=lane&15, row=(lane>>4)*4+reg  [verified m89/m91]
  const int rr = (lane >> 4) << 2;
  const int cc = lane & 15;
  if constexpr (MODE == 1) {
#pragma unroll
    for (int nt = 0; nt < 4; ++nt) {
      const long col = tn + wn + nt * 16 + cc;
      const float bj = bias[col];
#pragma unroll
      for (int mt = 0; mt < 4; ++mt) {
#pragma unroll
        for (int r = 0; r < 4; ++r) {
          const long row = tm + wm + mt * 16 + rr + r;
          const float q = acc[mt][nt][r] + bj;
          const f16 h = (f16)q;
          const f16 l = (f16)(q - (float)h);
          const long idx = (long)b * NNL + row * ND + col;
          Chi[idx] = h;
          Clo[idx] = l;
        }
      }
    }
  } else {
    const float g = (MODE == 0) ? gamma[0] : 0.0f;
#pragma unroll
    for (int mt = 0; mt < 4; ++mt) {
#pragma unroll
      for (int nt = 0; nt < 4; ++nt) {
#pragma unroll
        for (int r = 0; r < 4; ++r) {
          const long row = tm + wm + mt * 16 + rr + r;
          const long col = tn + wn + nt * 16 + cc;
          Cf[(long)b * NNL + row * ND + col] = acc[mt][nt][r] + g;
        }
      }
    }
  }
}

// ---------------- column-softmax stats (reduce over n, per column m) ----------
__global__ void stats_partial(const float* __restrict__ S, float* __restrict__ Mp,
                              float* __restrict__ Sp) {
  const int col = blockIdx.x * 256 + threadIdx.x;  // 0..2047
  const int seg = blockIdx.y;                      // 0..7 (n-split)
  const int b = blockIdx.z;
  const float* p = S + (long)b * NNL + (long)seg * 256 * ND + col;
  float m = -3.4e38f, s = 0.f;
  for (int n = 0; n < 256; ++n) {
    float x = p[(long)n * ND];
    float nm = fmaxf(m, x);
    s = s * __expf(m - nm) + __expf(x - nm);
    m = nm;
  }
  const long o = ((long)b * 8 + seg) * ND + col;
  Mp[o] = m;
  Sp[o] = s;
}

__global__ void stats_combine(const float* __restrict__ Mp, const float* __restrict__ Sp,
                              float* __restrict__ Mx, float* __restrict__ Rs) {
  const int col = blockIdx.x * 256 + threadIdx.x;
  const int b = blockIdx.y;
  float m = -3.4e38f, s = 0.f;
  for (int k = 0; k < 8; ++k) {
    const long o = ((long)b * 8 + k) * ND + col;
    float mk = Mp[o], sk = Sp[o];
    float nm = fmaxf(m, mk);
    s = s * __expf(m - nm) + sk * __expf(mk - nm);
    m = nm;
  }
  Mx[(long)b * ND + col] = m;
  Rs[(long)b * ND + col] = 1.0f / s;
}

// attn[b,m,e] = exp(S[b,m,e] - Mx[b,e]) * Rs[b,e]  -> fp16, same layout as S
__global__ void scale_exp_kernel(const float* __restrict__ S, const float* __restrict__ Mx,
                                 const float* __restrict__ Rs, f16* __restrict__ A) {
  const long i4 = (long)blockIdx.x * 256 + threadIdx.x;  // total/4
  const long i = i4 * 4;
  const int b = (int)(i >> 22);     // N*N = 2^22
  const int col = (int)(i & 2047);  // e index (multiple of 4)
  float4 s = reinterpret_cast<const float4*>(S)[i4];
  float4 m4 = *reinterpret_cast<const float4*>(&Mx[(long)b * ND + col]);
  float4 r4 = *reinterpret_cast<const float4*>(&Rs[(long)b * ND + col]);
  f16x4 o;
  o.x = (f16)(__expf(s.x - m4.x) * r4.x);
  o.y = (f16)(__expf(s.y - m4.y) * r4.y);
  o.z = (f16)(__expf(s.z - m4.z) * r4.z);
  o.w = (f16)(__expf(s.w - m4.w) * r4.w);
  reinterpret_cast<f16x4*>(A)[i4] = o;
}

// ---------------- launch ----------------
extern "C" void kernel_launch(void* const* d_in, const int* in_sizes, int n_in,
                              void* d_out, int out_size, void* d_ws, size_t ws_size,
                              hipStream_t stream) {
  (void)in_sizes; (void)n_in; (void)out_size;
  const float* X = (const float*)d_in[0];      // [8,2048,2048]
  const float* W = (const float*)d_in[1];      // [2048,2048]
  const float* bias = (const float*)d_in[2];   // [2048]
  const float* gamma = (const float*)d_in[3];  // scalar

  char* ws = (char*)d_ws;
  f16* Xhi = (f16*)(ws);
  f16* Xlo = (f16*)(ws + 67108864L);
  f16* Whi = (f16*)(ws + 134217728L);
  f16* Qhi = (f16*)(ws + 142606336L);
  f16* Qlo = (f16*)(ws + 209715200L);
  float* S = (float*)(ws + 276824064L);
  float* Mp = (float*)(ws + 411041792L);
  float* Sp = (float*)(ws + 411566080L);
  float* Mx = (float*)(ws + 412090368L);
  float* Rs = (float*)(ws + 412155904L);
  f16* Amat = Qhi;  // overlay: Q dead after GEMM2 (stream-ordered)
  if (ws_size < 412221440UL) return;

  split_x_f16<<<32768, 256, 0, stream>>>(X, Xhi, Xlo, 8388608);
  split_w_f16<<<4096, 256, 0, stream>>>(W, Whi, 1048576);

  dim3 gg(16, 16, 8), bb(256);
  // Q[b,n,f] = sum_e X[b,n,e] W[f,e] + bias[f]  -> fp16 split
  gemm_bt<1><<<gg, bb, 0, stream>>>(Xhi, Xlo, NNL, Whi, 0L, bias, nullptr,
                                    nullptr, Qhi, Qlo);
  // S[b,n,m] = sum_e Q[b,n,e] X[b,m,e] + gamma  -> fp32
  gemm_bt<0><<<gg, bb, 0, stream>>>(Qhi, Qlo, NNL, Xhi, NNL, nullptr, gamma,
                                    S, nullptr, nullptr);
  stats_partial<<<dim3(8, 8, 8), 256, 0, stream>>>(S, Mp, Sp);
  stats_combine<<<dim3(8, 8), 256, 0, stream>>>(Mp, Sp, Mx, Rs);
  scale_exp_kernel<<<32768, 256, 0, stream>>>(S, Mx, Rs, Amat);
  // out[b,n,m] = sum_e X[b,n,e] attn[b,m,e]  -> fp32 d_out
  gemm_bt<2><<<gg, bb, 0, stream>>>(Xhi, nullptr, NNL, Amat, NNL, nullptr,
                                    nullptr, (float*)d_out, nullptr, nullptr);
}

// Round 3
// 802.154 us; speedup vs baseline: 1.6446x; 1.4361x over previous
//
#include <hip/hip_runtime.h>
#include <stdint.h>

// B=8, N=E=2048.  All-fp16 single-product pipeline:
//  1) Xh = fp16(X), Wh = fp16(W)
//  2) Q = Xh·Wh^T + b   -> fp16 Qh
//  3) S = Qh·Xh^T + gamma -> fp32
//  4) column softmax stats over n (split-8 + combine)
//  5) attn[b,m,e] = exp(S-M)*R -> fp16 (overlays Qh)
//  6) out = Xh·attn^T -> fp32
// Error budget: score noise sigma ~0.020 (measured: absmax was insensitive to
// a 28x score-noise increase round1->round2, so tie-term is buried); dominant
// absmax term is GEMM3 fp16 rounding ~0.06.  Threshold 0.205.
//
// LDS bank-conflict swizzle: tile rows are 64 B = 16 banks, so rows r, r+2
// alias (8-way conflicts, 2.5e7 counted in round 2).  We store 16-B segment
// s_lds = s_g ^ ((r>>1)&3) -- applied on the GLOBAL fetch address because
// global_load_lds forces LDS dest = base + lane*16 -- and read with the
// inverse.  16-row sweeps then hit each bank-quad exactly twice (2-way = free).

typedef _Float16 f16;
typedef f16 f16x8 __attribute__((ext_vector_type(8)));
typedef f16 f16x4 __attribute__((ext_vector_type(4)));
typedef float f32x4 __attribute__((ext_vector_type(4)));

#define ND 2048
#define NNL 4194304L  // ND*ND

static __device__ __forceinline__ void stage16(const void* g, void* l) {
  __builtin_amdgcn_global_load_lds(
      (const __attribute__((address_space(1))) uint32_t*)g,
      (__attribute__((address_space(3))) uint32_t*)l, 16, 0, 0);
}

// ---------------- fp32 -> fp16 convert ----------------
__global__ void cvt_f16(const float* __restrict__ x, f16* __restrict__ h, int n4) {
  int i = blockIdx.x * 256 + threadIdx.x;
  if (i >= n4) return;
  float4 v = reinterpret_cast<const float4*>(x)[i];
  f16x4 o;
  o.x = (f16)v.x; o.y = (f16)v.y; o.z = (f16)v.z; o.w = (f16)v.w;
  reinterpret_cast<f16x4*>(h)[i] = o;
}

// ---------------- GEMM: C[i,j] = dot(A[i,:], B[j,:])  (row-major, K=2048)
// MODE 1: epilogue + bias[j], fp16 store
// MODE 0: epilogue + optional gamma scalar, fp32 store
template <int MODE>
__launch_bounds__(256) __global__
void gemm_bt(const f16* __restrict__ A, long sA, const f16* __restrict__ B, long sB,
             const float* __restrict__ bias, const float* __restrict__ gamma,
             float* __restrict__ Cf, f16* __restrict__ Ch) {
  __shared__ f16 smem[2 * 4096];  // two 128x32 fp16 tiles (8 KB each)

  const int b = blockIdx.z;
  const long tm = (long)blockIdx.y * 128;
  const long tn = (long)blockIdx.x * 128;
  const int tid = threadIdx.x;
  const int wave = tid >> 6;
  const int lane = tid & 63;
  const int wm = (wave >> 1) << 6;  // wave 2x2 grid, 64x64 each
  const int wn = (wave & 1) << 6;

  const f16* tp[2] = {A + b * sA + tm * ND, B + b * sB + tn * ND};

  // staging: 16 chunks of 16 rows (A:0-7, B:8-15); wave owns 4 consecutive.
  // lane -> row_local = L>>2, s_lds = L&3; fetch global seg s_g = s_lds ^
  // ((row>>1)&3) = (L&3)^((L>>3)&3).  LDS dest = chunk_base + lane*16.
  const char* gb[4];
  uint32_t loff[4];
#pragma unroll
  for (int i = 0; i < 4; ++i) {
    const int c = wave * 4 + i;
    const int t = c >> 3;
    const int r0 = (c & 7) * 16;
    const int sg = (lane & 3) ^ ((lane >> 3) & 3);
    gb[i] = (const char*)tp[t] + (long)(r0 + (lane >> 2)) * (ND * 2) + sg * 16;
    loff[i] = t * 8192 + (c & 7) * 1024 + lane * 16;
  }

  f32x4 acc[4][4] = {};
  // reader: row = wm/wn + (lane&15) + mt*16, seg s_g = lane>>4,
  // LDS seg = s_g ^ ((row>>1)&3); row's low bits come only from lane&15.
  const int swz = (((lane >> 4) ^ ((lane >> 1) & 3)) << 3);
  const int arow = (wm + (lane & 15)) * 32 + swz;
  const int brow = (wn + (lane & 15)) * 32 + swz;

  for (int k0 = 0; k0 < ND; k0 += 32) {
#pragma unroll
    for (int i = 0; i < 4; ++i)
      stage16(gb[i] + (long)k0 * 2, (char*)smem + loff[i]);
    asm volatile("s_waitcnt vmcnt(0)" ::: "memory");
    __syncthreads();

    f16x8 ah[4], bh[4];
#pragma unroll
    for (int t = 0; t < 4; ++t) {
      ah[t] = *(const f16x8*)&smem[arow + t * 512];
      bh[t] = *(const f16x8*)&smem[4096 + brow + t * 512];
    }
#pragma unroll
    for (int mt = 0; mt < 4; ++mt) {
#pragma unroll
      for (int nt = 0; nt < 4; ++nt) {
        acc[mt][nt] = __builtin_amdgcn_mfma_f32_16x16x32_f16(ah[mt], bh[nt], acc[mt][nt], 0, 0, 0);
      }
    }
    __syncthreads();
  }

  // epilogue: C/D layout col=lane&15, row=(lane>>4)*4+reg  [verified m89/m91]
  const int rr = (lane >> 4) << 2;
  const int cc = lane & 15;
  if constexpr (MODE == 1) {
#pragma unroll
    for (int nt = 0; nt < 4; ++nt) {
      const long col = tn + wn + nt * 16 + cc;
      const float bj = bias[col];
#pragma unroll
      for (int mt = 0; mt < 4; ++mt) {
#pragma unroll
        for (int r = 0; r < 4; ++r) {
          const long row = tm + wm + mt * 16 + rr + r;
          Ch[(long)b * NNL + row * ND + col] = (f16)(acc[mt][nt][r] + bj);
        }
      }
    }
  } else {
    const float g = gamma ? gamma[0] : 0.0f;
#pragma unroll
    for (int mt = 0; mt < 4; ++mt) {
#pragma unroll
      for (int nt = 0; nt < 4; ++nt) {
#pragma unroll
        for (int r = 0; r < 4; ++r) {
          const long row = tm + wm + mt * 16 + rr + r;
          const long col = tn + wn + nt * 16 + cc;
          Cf[(long)b * NNL + row * ND + col] = acc[mt][nt][r] + g;
        }
      }
    }
  }
}

// ---------------- column-softmax stats (reduce over n, per column m) ----------
__global__ void stats_partial(const float* __restrict__ S, float* __restrict__ Mp,
                              float* __restrict__ Sp) {
  const int col = blockIdx.x * 256 + threadIdx.x;  // 0..2047
  const int seg = blockIdx.y;                      // 0..7 (n-split)
  const int b = blockIdx.z;
  const float* p = S + (long)b * NNL + (long)seg * 256 * ND + col;
  float m = -3.4e38f, s = 0.f;
  for (int n = 0; n < 256; ++n) {
    float x = p[(long)n * ND];
    float nm = fmaxf(m, x);
    s = s * __expf(m - nm) + __expf(x - nm);
    m = nm;
  }
  const long o = ((long)b * 8 + seg) * ND + col;
  Mp[o] = m;
  Sp[o] = s;
}

__global__ void stats_combine(const float* __restrict__ Mp, const float* __restrict__ Sp,
                              float* __restrict__ Mx, float* __restrict__ Rs) {
  const int col = blockIdx.x * 256 + threadIdx.x;
  const int b = blockIdx.y;
  float m = -3.4e38f, s = 0.f;
  for (int k = 0; k < 8; ++k) {
    const long o = ((long)b * 8 + k) * ND + col;
    float mk = Mp[o], sk = Sp[o];
    float nm = fmaxf(m, mk);
    s = s * __expf(m - nm) + sk * __expf(mk - nm);
    m = nm;
  }
  Mx[(long)b * ND + col] = m;
  Rs[(long)b * ND + col] = 1.0f / s;
}

// attn[b,m,e] = exp(S[b,m,e] - Mx[b,e]) * Rs[b,e]  -> fp16, same layout as S
__global__ void scale_exp_kernel(const float* __restrict__ S, const float* __restrict__ Mx,
                                 const float* __restrict__ Rs, f16* __restrict__ A) {
  const long i4 = (long)blockIdx.x * 256 + threadIdx.x;  // total/4
  const long i = i4 * 4;
  const int b = (int)(i >> 22);     // N*N = 2^22
  const int col = (int)(i & 2047);  // e index (multiple of 4)
  float4 s = reinterpret_cast<const float4*>(S)[i4];
  float4 m4 = *reinterpret_cast<const float4*>(&Mx[(long)b * ND + col]);
  float4 r4 = *reinterpret_cast<const float4*>(&Rs[(long)b * ND + col]);
  f16x4 o;
  o.x = (f16)(__expf(s.x - m4.x) * r4.x);
  o.y = (f16)(__expf(s.y - m4.y) * r4.y);
  o.z = (f16)(__expf(s.z - m4.z) * r4.z);
  o.w = (f16)(__expf(s.w - m4.w) * r4.w);
  reinterpret_cast<f16x4*>(A)[i4] = o;
}

// ---------------- launch ----------------
extern "C" void kernel_launch(void* const* d_in, const int* in_sizes, int n_in,
                              void* d_out, int out_size, void* d_ws, size_t ws_size,
                              hipStream_t stream) {
  (void)in_sizes; (void)n_in; (void)out_size;
  const float* X = (const float*)d_in[0];      // [8,2048,2048]
  const float* W = (const float*)d_in[1];      // [2048,2048]
  const float* bias = (const float*)d_in[2];   // [2048]
  const float* gamma = (const float*)d_in[3];  // scalar

  char* ws = (char*)d_ws;
  f16* Xh = (f16*)(ws);                      // 67,108,864 B
  f16* Wh = (f16*)(ws + 67108864L);          //  8,388,608 B
  f16* Qh = (f16*)(ws + 75497472L);          // 67,108,864 B
  float* S = (float*)(ws + 142606336L);      // 134,217,728 B
  float* Mp = (float*)(ws + 276824064L);     //    524,288 B
  float* Sp = (float*)(ws + 277348352L);     //    524,288 B
  float* Mx = (float*)(ws + 277872640L);     //     65,536 B
  float* Rs = (float*)(ws + 277938176L);     //     65,536 B
  f16* Amat = Qh;  // overlay: Q dead after GEMM2 (stream-ordered)
  if (ws_size < 278003712UL) return;

  cvt_f16<<<32768, 256, 0, stream>>>(X, Xh, 8388608);
  cvt_f16<<<4096, 256, 0, stream>>>(W, Wh, 1048576);

  dim3 gg(16, 16, 8), bb(256);
  // Q[b,n,f] = sum_e X[b,n,e] W[f,e] + bias[f]  -> fp16
  gemm_bt<1><<<gg, bb, 0, stream>>>(Xh, NNL, Wh, 0L, bias, nullptr, nullptr, Qh);
  // S[b,n,m] = sum_e Q[b,n,e] X[b,m,e] + gamma  -> fp32
  gemm_bt<0><<<gg, bb, 0, stream>>>(Qh, NNL, Xh, NNL, nullptr, gamma, S, nullptr);
  stats_partial<<<dim3(8, 8, 8), 256, 0, stream>>>(S, Mp, Sp);
  stats_combine<<<dim3(8, 8), 256, 0, stream>>>(Mp, Sp, Mx, Rs);
  scale_exp_kernel<<<32768, 256, 0, stream>>>(S, Mx, Rs, Amat);
  // out[b,n,m] = sum_e X[b,n,e] attn[b,m,e]  -> fp32 d_out
  gemm_bt<0><<<gg, bb, 0, stream>>>(Xh, NNL, Amat, NNL, nullptr, nullptr,
                                    (float*)d_out, nullptr);
}